// Round 5
// baseline (352.439 us; speedup 1.0000x reference)
//
#include <hip/hip_runtime.h>

// MultiHeadAttention: B=4, S=2048, D=1024, H=16, dk=64. fp32 I/O, bf16 internal.
//
// Round-10 (round-9 counters: attn fell below 94us; gemm_qkv now longest at
// 94.4us = 546 TF, MfmaUtil 22.6 / VALU 12 / HBM 14 -> structure-stall-bound,
// within-structure fixes known-null):
//   - cvt_x3 ELIMINATED: gemm_qkv reg-stages A directly from the fp32 inputs
//     (T14 issue-early/write-late: float4 loads at iter top -> MFMA phase
//     hides latency -> f2bf + ds_write_b128 pre-barrier). LDS bytes are
//     bit-identical to the old cvt_x3 + global_load_lds path (same RNE f2bf,
//     same swizzle algebra), so numerics unchanged. B keeps global_load_lds.
//     Removes ~144MB of HBM round-trip + one kernel launch (~25us).
//   - attn: s_setprio(1) around QK and PV MFMA clusters (m191: +4-7% on
//     co-resident independent-block attn; pure scheduler hint).
//   - workspace: single 75.5MB layout (Qb,Kb,VtG,Ob,Wc); fallback path gone.
// Attention math / GEMM inner loops byte-identical to verified round-9
// (absmax 4.88e-4).

typedef unsigned short u16;
typedef __attribute__((ext_vector_type(8))) short short8;   // 8 bf16 = 4 VGPRs
typedef __attribute__((ext_vector_type(4))) float f32x4;

__device__ __forceinline__ u16 f2bf(float f) {               // RNE (epilogues)
  union { float f; unsigned int u; } v; v.f = f;
  return (u16)((v.u + 0x7FFFu + ((v.u >> 16) & 1u)) >> 16);
}

__device__ __forceinline__ void gll16(const void* gptr, void* lptr) {
  __builtin_amdgcn_global_load_lds(
      (const __attribute__((address_space(1))) unsigned int*)gptr,
      (__attribute__((address_space(3))) unsigned int*)lptr, 16, 0, 0);
}

// convert 8 fp32 -> 8 bf16 (RNE, identical to cvt_x3) and store 16B to LDS
__device__ __forceinline__ void cvt_store8(u16* lds, f32x4 a, f32x4 b) {
  short8 r;
  r[0] = (short)f2bf(a[0]); r[1] = (short)f2bf(a[1]);
  r[2] = (short)f2bf(a[2]); r[3] = (short)f2bf(a[3]);
  r[4] = (short)f2bf(b[0]); r[5] = (short)f2bf(b[1]);
  r[6] = (short)f2bf(b[2]); r[7] = (short)f2bf(b[3]);
  *(short8*)lds = r;
}

// ---------------------------------------------------------------- converts
__global__ void cvt_w4(const float* __restrict__ w0, const float* __restrict__ w1,
                       const float* __restrict__ w2, const float* __restrict__ w3,
                       u16* __restrict__ d) {
  const int z = blockIdx.y;
  const float* s = (z == 0) ? w0 : (z == 1) ? w1 : (z == 2) ? w2 : w3;
  const int i = (blockIdx.x * 256 + threadIdx.x) * 8;
  u16* dz = d + (size_t)z * 1048576;
  f32x4 a = *(const f32x4*)(s + i);
  f32x4 b = *(const f32x4*)(s + i + 4);
  short8 r;
  r[0] = (short)f2bf(a[0]); r[1] = (short)f2bf(a[1]);
  r[2] = (short)f2bf(a[2]); r[3] = (short)f2bf(a[3]);
  r[4] = (short)f2bf(b[0]); r[5] = (short)f2bf(b[1]);
  r[6] = (short)f2bf(b[2]); r[7] = (short)f2bf(b[3]);
  *(short8*)(dz + i) = r;
}

// XCD-aware tile swizzle: consecutive dispatch ids round-robin across the 8
// XCDs; remap so each XCD owns a CONTIGUOUS run of M-strips (A-panel + W
// L2-resident). Bijective iff nwg % 8 == 0 (true for all our grids).
__device__ __forceinline__ void xcd_swz(unsigned& bx, unsigned& by) {
  const unsigned nx = gridDim.x, nwg = nx * gridDim.y;
  if ((nwg & 7u) == 0u) {
    const unsigned lin = bx + nx * by;
    const unsigned swz = (lin & 7u) * (nwg >> 3) + (lin >> 3);
    bx = swz % nx;
    by = swz / nx;
  }
}

// ---------------------------------------------------------------- GEMM
// C[m][n] = (sum_k A[m][k]*W[n][k] + bias[n]) * scale; 128x128 tile, GK=32,
// dbuf staging. TRANS: write C^T[n][m] (for V^T) with packed b64 stores.
#define GM 128
#define GN 128
#define GK 32

template <typename TC, bool TRANS>
__global__ __launch_bounds__(256, 3) void gemm_bb(
    const u16* __restrict__ A, const u16* __restrict__ W,
    const float* __restrict__ bias, TC* __restrict__ C,
    int M, int N, int K, float scale)
{
  __shared__ __align__(16) u16 As[2][GM * GK];   // 16 KB
  __shared__ __align__(16) u16 Bs[2][GN * GK];   // 16 KB

  const int tid  = threadIdx.x;
  const int lane = tid & 63;
  const int l15  = lane & 15;
  const int quad = lane >> 4;
  const int wave = tid >> 6;
  unsigned bxu = blockIdx.x, byu = blockIdx.y;
  xcd_swz(bxu, byu);
  const int bm = byu * GM;
  const int bn = bxu * GN;
  const int wm = (wave >> 1) * 64;
  const int wn = (wave & 1) * 64;

  const f32x4 zero4 = {0.f, 0.f, 0.f, 0.f};
  f32x4 acc[4][4];
#pragma unroll
  for (int i = 0; i < 4; i++)
#pragma unroll
    for (int j = 0; j < 4; j++) acc[i][j] = zero4;

  const int srow = tid >> 2;
  const int chl  = (tid & 3) ^ ((tid >> 3) & 3);
  const u16* Ag = A + (size_t)(bm + srow) * K + chl * 8;
  const u16* Wg = W + (size_t)(bn + srow) * K + chl * 8;
  const size_t rowskip = (size_t)64 * K;
  const int chpA = quad ^ ((l15 >> 1) & 3);

  gll16(Ag, &As[0][tid * 8]);
  gll16(Ag + rowskip, &As[0][tid * 8 + 2048]);
  gll16(Wg, &Bs[0][tid * 8]);
  gll16(Wg + rowskip, &Bs[0][tid * 8 + 2048]);

  int buf = 0;
  for (int k0 = 0; k0 < K; k0 += GK) {
    __syncthreads();
    if (k0 + GK < K) {
      const int nb = buf ^ 1;
      gll16(Ag + k0 + GK, &As[nb][tid * 8]);
      gll16(Ag + k0 + GK + rowskip, &As[nb][tid * 8 + 2048]);
      gll16(Wg + k0 + GK, &Bs[nb][tid * 8]);
      gll16(Wg + k0 + GK + rowskip, &Bs[nb][tid * 8 + 2048]);
    }

    short8 af[4], bfr[4];
#pragma unroll
    for (int mi = 0; mi < 4; mi++)
      af[mi] = *(const short8*)&As[buf][(wm + mi * 16 + l15) * GK + chpA * 8];
#pragma unroll
    for (int ni = 0; ni < 4; ni++)
      bfr[ni] = *(const short8*)&Bs[buf][(wn + ni * 16 + l15) * GK + chpA * 8];
#pragma unroll
    for (int mi = 0; mi < 4; mi++)
#pragma unroll
      for (int ni = 0; ni < 4; ni++)
        acc[mi][ni] = __builtin_amdgcn_mfma_f32_16x16x32_bf16(
            af[mi], bfr[ni], acc[mi][ni], 0, 0, 0);
    buf ^= 1;
  }

  float bval[4];
#pragma unroll
  for (int ni = 0; ni < 4; ni++) bval[ni] = bias[bn + wn + ni * 16 + l15];
#pragma unroll
  for (int mi = 0; mi < 4; mi++) {
    const int m0 = bm + wm + mi * 16 + quad * 4;
#pragma unroll
    for (int ni = 0; ni < 4; ni++) {
      const int n = bn + wn + ni * 16 + l15;
      if constexpr (TRANS) {
        ushort4 w;
        w.x = f2bf((acc[mi][ni][0] + bval[ni]) * scale);
        w.y = f2bf((acc[mi][ni][1] + bval[ni]) * scale);
        w.z = f2bf((acc[mi][ni][2] + bval[ni]) * scale);
        w.w = f2bf((acc[mi][ni][3] + bval[ni]) * scale);
        *(ushort4*)((u16*)C + (size_t)n * M + m0) = w;
      } else {
#pragma unroll
        for (int r = 0; r < 4; r++) {
          const float v = (acc[mi][ni][r] + bval[ni]) * scale;
          if constexpr (sizeof(TC) == 2)
            C[(size_t)(m0 + r) * N + n] = f2bf(v);
          else
            C[(size_t)(m0 + r) * N + n] = v;
        }
      }
    }
  }
}

// z-batched QKV projection reading fp32 A DIRECTLY (cvt fused into staging):
// z=0 -> Qb (scaled), z=1 -> Kb, z=2 -> V^T (transposed store).
// A staging: issue float4 loads at iter top (latency hidden under MFMAs),
// f2bf + ds_write_b128 just before the barrier. LDS layout/content identical
// to the old cvt_x3 + global_load_lds path. B (bf16 weights) via gll16.
__global__ __launch_bounds__(256, 3) void gemm_qkv(
    const float* __restrict__ qf, const float* __restrict__ kf,
    const float* __restrict__ vf, const u16* __restrict__ Wc,
    const float* __restrict__ bq, const float* __restrict__ bk,
    const float* __restrict__ bv, u16* __restrict__ Qo,
    u16* __restrict__ Ko, u16* __restrict__ Vo, float qscale)
{
  const int M = 8192, N = 1024, K = 1024;
  const int z = blockIdx.z;
  const float* A = (z == 0) ? qf : (z == 1) ? kf : vf;
  const u16* W = Wc + (size_t)z * 1048576;
  const float* bias = (z == 0) ? bq : (z == 1) ? bk : bv;
  u16* C = (z == 0) ? Qo : (z == 1) ? Ko : Vo;
  const float scale = (z == 0) ? qscale : 1.0f;
  const bool trans = (z == 2);

  __shared__ __align__(16) u16 As[2][GM * GK];
  __shared__ __align__(16) u16 Bs[2][GN * GK];

  const int tid  = threadIdx.x;
  const int lane = tid & 63;
  const int l15  = lane & 15;
  const int quad = lane >> 4;
  const int wave = tid >> 6;
  unsigned bxu = blockIdx.x, byu = blockIdx.y;
  xcd_swz(bxu, byu);
  const int bm = byu * GM;
  const int bn = bxu * GN;
  const int wm = (wave >> 1) * 64;
  const int wn = (wave & 1) * 64;

  const f32x4 zero4 = {0.f, 0.f, 0.f, 0.f};
  f32x4 acc[4][4];
#pragma unroll
  for (int i = 0; i < 4; i++)
#pragma unroll
    for (int j = 0; j < 4; j++) acc[i][j] = zero4;

  const int srow = tid >> 2;
  const int chl  = (tid & 3) ^ ((tid >> 3) & 3);
  const float* Af = A + (size_t)(bm + srow) * K + chl * 8;   // fp32 source
  const u16* Wg = W + (size_t)(bn + srow) * K + chl * 8;
  const size_t rowskip  = (size_t)64 * K;
  const int chpA = quad ^ ((l15 >> 1) & 3);

  // prologue: stage A[0] (reg->cvt->LDS) and B[0] (gll16)
  {
    f32x4 a0 = *(const f32x4*)(Af);
    f32x4 a1 = *(const f32x4*)(Af + 4);
    f32x4 a2 = *(const f32x4*)(Af + rowskip);
    f32x4 a3 = *(const f32x4*)(Af + rowskip + 4);
    cvt_store8(&As[0][tid * 8], a0, a1);
    cvt_store8(&As[0][tid * 8 + 2048], a2, a3);
  }
  gll16(Wg, &Bs[0][tid * 8]);
  gll16(Wg + rowskip, &Bs[0][tid * 8 + 2048]);

  int buf = 0;
  for (int k0 = 0; k0 < K; k0 += GK) {
    __syncthreads();
    const bool more = (k0 + GK < K);
    f32x4 a0, a1, a2, a3;
    if (more) {
      const int nb = buf ^ 1;
      const float* Ap = Af + k0 + GK;
      a0 = *(const f32x4*)(Ap);                 // issue-early: latency hidden
      a1 = *(const f32x4*)(Ap + 4);             //   under the MFMA phase
      a2 = *(const f32x4*)(Ap + rowskip);
      a3 = *(const f32x4*)(Ap + rowskip + 4);
      gll16(Wg + k0 + GK, &Bs[nb][tid * 8]);
      gll16(Wg + k0 + GK + rowskip, &Bs[nb][tid * 8 + 2048]);
    }

    short8 af[4], bfr[4];
#pragma unroll
    for (int mi = 0; mi < 4; mi++)
      af[mi] = *(const short8*)&As[buf][(wm + mi * 16 + l15) * GK + chpA * 8];
#pragma unroll
    for (int ni = 0; ni < 4; ni++)
      bfr[ni] = *(const short8*)&Bs[buf][(wn + ni * 16 + l15) * GK + chpA * 8];
#pragma unroll
    for (int mi = 0; mi < 4; mi++)
#pragma unroll
      for (int ni = 0; ni < 4; ni++)
        acc[mi][ni] = __builtin_amdgcn_mfma_f32_16x16x32_bf16(
            af[mi], bfr[ni], acc[mi][ni], 0, 0, 0);

    if (more) {                                 // write-late, pre-barrier
      const int nb = buf ^ 1;
      cvt_store8(&As[nb][tid * 8], a0, a1);
      cvt_store8(&As[nb][tid * 8 + 2048], a2, a3);
    }
    buf ^= 1;
  }

  float bval[4];
#pragma unroll
  for (int ni = 0; ni < 4; ni++) bval[ni] = bias[bn + wn + ni * 16 + l15];
#pragma unroll
  for (int mi = 0; mi < 4; mi++) {
    const int m0 = bm + wm + mi * 16 + quad * 4;
#pragma unroll
    for (int ni = 0; ni < 4; ni++) {
      const int n = bn + wn + ni * 16 + l15;
      if (trans) {
        ushort4 w;
        w.x = f2bf(acc[mi][ni][0] + bval[ni]);
        w.y = f2bf(acc[mi][ni][1] + bval[ni]);
        w.z = f2bf(acc[mi][ni][2] + bval[ni]);
        w.w = f2bf(acc[mi][ni][3] + bval[ni]);
        *(ushort4*)(C + (size_t)n * M + m0) = w;
      } else {
#pragma unroll
        for (int r = 0; r < 4; r++)
          C[(size_t)(m0 + r) * N + n] = f2bf((acc[mi][ni][r] + bval[ni]) * scale);
      }
    }
  }
}

// ---------------------------------------------------------------- attention
// grid (S/128, B*H) XCD-swizzled; 4 waves x 32 q-rows; 64-key tiles; K and V
// both single-buffered (V staged during QK, K_{i+1} staged during PV);
// 2 barriers/iter; 32KB LDS -> 4 blocks/CU. Per-tile unmasked bitmap skips
// all mask work on open tiles. S^T orientation; exact softmax.
// Q arrives pre-scaled by (1/sqrt(dk))*log2(e). Math identical to round-6/8/9.
// setprio(1) wraps the MFMA clusters (m191: helps co-resident attn blocks).
__global__ __launch_bounds__(256, 4) void attn_fused(
    const u16* __restrict__ Qb, const u16* __restrict__ Kb,
    const u16* __restrict__ VtG, const int* __restrict__ mask,
    u16* __restrict__ Ob)
{
  constexpr int S = 2048, D = 1024;
  __shared__ __align__(16) u16 Ks[64 * 64];      // [s][dk], 16B chunks ^(s&7), 8KB
  __shared__ __align__(16) u16 Vs[64 * 64];      // [d][s],  16B chunks ^(d&7), 8KB
  __shared__ __align__(16) u16 Pt[4][32 * 64];   // [q][k],  16B chunks ^(q&7), 16KB

  const int tid  = threadIdx.x;
  const int lane = tid & 63;
  const int wave = tid >> 6;
  const int l15  = lane & 15;
  const int quad = lane >> 4;

  // XCD swizzle: 1024 wgs; XCD c owns swz in [128c,128c+128) -> 8 (b,h) pairs
  // (K/V 8 x 0.5MB = 4MB, L2-resident) x all 16 q-blocks.
  const int lin = blockIdx.x + 16 * blockIdx.y;
  const int swz = (lin & 7) * 128 + (lin >> 3);
  const int b  = swz >> 8;
  const int h  = (swz >> 4) & 15;
  const int qw = (swz & 15) * 128 + wave * 32;

  const u16* Qp = Qb + (size_t)b * S * D + h * 64;
  const u16* Kp = Kb + (size_t)b * S * D + h * 64;
  const u16* Vg = VtG + (size_t)h * 64 * 8192 + b * 2048;  // [dim][token]
  const int* mp = mask + b * S;

  // Q fragments (B-operand of S^T = K*Q^T; same per-lane layout as A-operand)
  short8 qf[2][2];
#pragma unroll
  for (int qb = 0; qb < 2; qb++)
#pragma unroll
    for (int c = 0; c < 2; c++)
      qf[qb][c] = *(const short8*)&Qp[(size_t)(qw + qb * 16 + l15) * D + c * 32 + quad * 8];

  const f32x4 zero4 = {0.f, 0.f, 0.f, 0.f};
  f32x4 o_acc[2][4];
#pragma unroll
  for (int qb = 0; qb < 2; qb++)
#pragma unroll
    for (int ni = 0; ni < 4; ni++) o_acc[qb][ni] = zero4;
  f32x4 l_acc[2] = {zero4, zero4};   // row-sums via ones-MFMA (same C-layout as o_acc)

  const short8 one8 = {(short)0x3f80, (short)0x3f80, (short)0x3f80, (short)0x3f80,
                       (short)0x3f80, (short)0x3f80, (short)0x3f80, (short)0x3f80};

  // staging (round-4 verified): phys chunk tid&7 of row p*32+(tid>>3),
  // logical = phys ^ (row&7), swizzle applied on the GLOBAL column.
  const int srow = tid >> 3;
  const int chl  = (tid & 7) ^ (srow & 7);
  const int fsw  = l15 & 7;

  // ---- per-64-key-tile "fully unmasked" bitmap (32 tiles). tbs aliases the
  // first 16B of Pt: read into registers (post-sync) strictly before any Pt
  // write (which only happens after the loop-top barrier).
  unsigned int* tbs = (unsigned int*)&Pt[0][0];
  {
    const int t8 = tid * 8;                    // 256 threads x 8 ints = 2048
    int4 a  = *(const int4*)&mp[t8];
    int4 c4 = *(const int4*)&mp[t8 + 4];
    int ok = ((a.x & a.y & a.z & a.w & c4.x & c4.y & c4.z & c4.w) != 0);
    unsigned long long bb = __ballot(ok);      // lane i covers tile w*8+(i>>3)
    if (lane == 0) {
      unsigned int byt = 0;
#pragma unroll
      for (int g = 0; g < 8; g++)
        if (((bb >> (8 * g)) & 0xffull) == 0xffull) byt |= 1u << g;
      tbs[wave] = byt;
    }
  }

  // pre-loop: stage K_0
#pragma unroll
  for (int p = 0; p < 2; p++)
    gll16(Kp + (size_t)(p * 32 + srow) * D + chl * 8, &Ks[p * 2048 + tid * 8]);

  __syncthreads();
  const unsigned int tilebits = __builtin_amdgcn_readfirstlane(
      tbs[0] | (tbs[1] << 8) | (tbs[2] << 16) | (tbs[3] << 24));

  for (int kt = 0; kt < S; kt += 64) {
    __syncthreads();   // A: K_kt landed (staged post-B of prev iter / prologue);
                       //    Vs + Pt free (prev PV reads done).

    // stage V_kt (drained at barrier B, overlapped with QK+softmax)
#pragma unroll
    for (int p = 0; p < 2; p++)
      gll16(Vg + (size_t)(p * 32 + srow) * 8192 + kt + chl * 8,
            &Vs[p * 2048 + tid * 8]);

    // ---- S^T = K Q^T : sc[qb][s], rows=keys s*16+quad*4+r, col q=l15
    f32x4 sc[2][4];
#pragma unroll
    for (int qb = 0; qb < 2; qb++)
#pragma unroll
      for (int s = 0; s < 4; s++) sc[qb][s] = zero4;
    __builtin_amdgcn_s_setprio(1);
#pragma unroll
    for (int c = 0; c < 2; c++)
#pragma unroll
      for (int s = 0; s < 4; s++) {
        short8 kf = *(const short8*)
            &Ks[(s * 16 + l15) * 64 + ((c * 4 + quad) ^ fsw) * 8];
        sc[0][s] = __builtin_amdgcn_mfma_f32_16x16x32_bf16(kf, qf[0][c], sc[0][s], 0, 0, 0);
        sc[1][s] = __builtin_amdgcn_mfma_f32_16x16x32_bf16(kf, qf[1][c], sc[1][s], 0, 0, 0);
      }
    __builtin_amdgcn_s_setprio(0);

    // ---- P^T = exp2(sc [+ mask]); truncate+pack 2 keys per v_perm_b32
    const bool open = (tilebits >> (kt >> 6)) & 1;   // wave-uniform (sgpr)
    if (open) {
#pragma unroll
      for (int qb = 0; qb < 2; qb++) {
        const int qrow = qb * 16 + l15;
#pragma unroll
        for (int s = 0; s < 4; s++) {
          unsigned int t[4];
#pragma unroll
          for (int r = 0; r < 4; r++) {
            union { float f; unsigned int u; } pu;
            pu.f = __builtin_amdgcn_exp2f(sc[qb][s][r]);
            t[r] = pu.u;
          }
          uint2 w;
          w.x = __builtin_amdgcn_perm(t[1], t[0], 0x07060302u);  // keys +0,+1
          w.y = __builtin_amdgcn_perm(t[3], t[2], 0x07060302u);  // keys +2,+3
          const int phys = (s * 2 + (quad >> 1)) ^ fsw;
          *(uint2*)&Pt[wave][qrow * 64 + phys * 8 + (quad & 1) * 4] = w;
        }
      }
    } else {
      f32x4 cm[4];
#pragma unroll
      for (int s = 0; s < 4; s++) {
        int4 mv = *(const int4*)&mp[kt + s * 16 + quad * 4];
        cm[s][0] = mv.x ? 0.f : -1.0e9f;
        cm[s][1] = mv.y ? 0.f : -1.0e9f;
        cm[s][2] = mv.z ? 0.f : -1.0e9f;
        cm[s][3] = mv.w ? 0.f : -1.0e9f;
      }
#pragma unroll
      for (int qb = 0; qb < 2; qb++) {
        const int qrow = qb * 16 + l15;
#pragma unroll
        for (int s = 0; s < 4; s++) {
          unsigned int t[4];
#pragma unroll
          for (int r = 0; r < 4; r++) {
            union { float f; unsigned int u; } pu;
            pu.f = __builtin_amdgcn_exp2f(sc[qb][s][r] + cm[s][r]);
            t[r] = pu.u;
          }
          uint2 w;
          w.x = __builtin_amdgcn_perm(t[1], t[0], 0x07060302u);
          w.y = __builtin_amdgcn_perm(t[3], t[2], 0x07060302u);
          const int phys = (s * 2 + (quad >> 1)) ^ fsw;
          *(uint2*)&Pt[wave][qrow * 64 + phys * 8 + (quad & 1) * 4] = w;
        }
      }
    }

    __syncthreads();   // B: V_kt landed; all waves' QK reads of Ks done.

    // stage K_{kt+64} into Ks (safe post-B; drained at next barrier A),
    // overlapped with PV below.
    if (kt + 64 < S) {
#pragma unroll
      for (int p = 0; p < 2; p++)
        gll16(Kp + (size_t)(kt + 64 + p * 32 + srow) * D + chl * 8,
              &Ks[p * 2048 + tid * 8]);
    }

    // ---- O += P V ; l += P 1  (A = pf from Pt rows; same-wave Pt
    //      write->read, DS in-order per wave)
    __builtin_amdgcn_s_setprio(1);
#pragma unroll
    for (int c = 0; c < 2; c++) {
      short8 pf[2];
#pragma unroll
      for (int qb = 0; qb < 2; qb++)
        pf[qb] = *(const short8*)
            &Pt[wave][(qb * 16 + l15) * 64 + ((c * 4 + quad) ^ fsw) * 8];
      l_acc[0] = __builtin_amdgcn_mfma_f32_16x16x32_bf16(pf[0], one8, l_acc[0], 0, 0, 0);
      l_acc[1] = __builtin_amdgcn_mfma_f32_16x16x32_bf16(pf[1], one8, l_acc[1], 0, 0, 0);
#pragma unroll
      for (int ni = 0; ni < 4; ni++) {
        short8 vf = *(const short8*)
            &Vs[(ni * 16 + l15) * 64 + ((c * 4 + quad) ^ fsw) * 8];
        o_acc[0][ni] = __builtin_amdgcn_mfma_f32_16x16x32_bf16(pf[0], vf, o_acc[0][ni], 0, 0, 0);
        o_acc[1][ni] = __builtin_amdgcn_mfma_f32_16x16x32_bf16(pf[1], vf, o_acc[1][ni], 0, 0, 0);
      }
    }
    __builtin_amdgcn_s_setprio(0);
  }

  // ---- epilogue: l_acc reg r holds l for q-row qb*16+quad*4+r — exactly
  //      the o_acc row layout; no cross-lane reduction needed.
  float rl[2][4];
#pragma unroll
  for (int qb = 0; qb < 2; qb++)
#pragma unroll
    for (int r = 0; r < 4; r++) rl[qb][r] = 1.0f / l_acc[qb][r];
#pragma unroll
  for (int qb = 0; qb < 2; qb++) {
    const int q0 = qw + qb * 16 + quad * 4;
#pragma unroll
    for (int ni = 0; ni < 4; ni++)
#pragma unroll
      for (int r = 0; r < 4; r++)
        Ob[(size_t)(b * S + q0 + r) * D + h * 64 + ni * 16 + l15] =
            f2bf(o_acc[qb][ni][r] * rl[qb][r]);
  }
}

// ---------------------------------------------------------------- launch
extern "C" void kernel_launch(void* const* d_in, const int* in_sizes, int n_in,
                              void* d_out, int out_size, void* d_ws, size_t ws_size,
                              hipStream_t stream) {
  const int M = 8192, N = 1024, K = 1024;
  const float* q    = (const float*)d_in[0];
  const float* k    = (const float*)d_in[1];
  const float* v    = (const float*)d_in[2];
  const int*   mask = (const int*)d_in[3];
  const float* Wq = (const float*)d_in[4];
  const float* bq = (const float*)d_in[5];
  const float* Wk = (const float*)d_in[6];
  const float* bk = (const float*)d_in[7];
  const float* Wv = (const float*)d_in[8];
  const float* bv = (const float*)d_in[9];
  const float* Wo = (const float*)d_in[10];
  const float* bo = (const float*)d_in[11];

  const size_t MN = (size_t)M * N;                  // 8388608
  const float QSC = 0.125f * 1.44269504f;           // (1/sqrt(dk)) * log2(e)

  dim3 bb(256);
  dim3 gg(N / GN, M / GM);

  // single layout, 75.5 MB: Qb, Kb, VtG, Ob (bf16) + 4 weight matrices
  u16* Qb  = (u16*)d_ws;
  u16* Kb  = Qb + MN;
  u16* VtG = Kb + MN;                 // V^T: [1024 dims][8192 tokens]
  u16* Ob  = VtG + MN;                // attn output
  u16* Wc  = Ob + MN;                 // 4 x 1M bf16 weights

  cvt_w4<<<dim3(512, 4), bb, 0, stream>>>(Wq, Wk, Wv, Wo, Wc);
  gemm_qkv<<<dim3(8, 64, 3), bb, 0, stream>>>(q, k, v, Wc, bq, bk, bv,
                                              Qb, Kb, VtG, QSC);
  attn_fused<<<dim3(16, 64), bb, 0, stream>>>(Qb, Kb, VtG, mask, Ob);
  gemm_bb<float, false><<<gg, bb, 0, stream>>>(Ob, Wc + 3 * 1048576, bo,
                                               (float*)d_out, M, N, K, 1.0f);
}

// Round 6
// 336.793 us; speedup vs baseline: 1.0465x; 1.0465x over previous
//
#include <hip/hip_runtime.h>

// MultiHeadAttention: B=4, S=2048, D=1024, H=16, dk=64. fp32 I/O, bf16 internal.
//
// Round-11: round-10's fused fp32-A reg-staging REGRESSED gemm_qkv 94->143us
// (MfmaUtil 22.6->14.8: reg round-trip put HBM latency on the critical path;
// falsifier triggered). Reverted to the VERIFIED round-9 pipeline:
//   cvt(bf16 staging) -> gemm_qkv (bf16 A via global_load_lds) -> attn -> gemm.
// Deltas vs round-9 (all risk-free):
//   - cvt_w4 + cvt_x3 merged into ONE cvt_all launch (grid 4096x4); saves a
//     kernel boundary; identical bytes written.
//   - attn keeps s_setprio(1/0) around MFMA clusters (round-10-verified).
// gemm_qkv / attn math byte-identical to round-9 (absmax 4.88e-4).

typedef unsigned short u16;
typedef __attribute__((ext_vector_type(8))) short short8;   // 8 bf16 = 4 VGPRs
typedef __attribute__((ext_vector_type(4))) float f32x4;

__device__ __forceinline__ u16 f2bf(float f) {               // RNE (epilogues)
  union { float f; unsigned int u; } v; v.f = f;
  return (u16)((v.u + 0x7FFFu + ((v.u >> 16) & 1u)) >> 16);
}

__device__ __forceinline__ void gll16(const void* gptr, void* lptr) {
  __builtin_amdgcn_global_load_lds(
      (const __attribute__((address_space(1))) unsigned int*)gptr,
      (__attribute__((address_space(3))) unsigned int*)lptr, 16, 0, 0);
}

// ---------------------------------------------------------------- converts
__device__ __forceinline__ void cvt8(const float* __restrict__ s,
                                     u16* __restrict__ d) {
  f32x4 a = *(const f32x4*)(s);
  f32x4 b = *(const f32x4*)(s + 4);
  short8 r;
  r[0] = (short)f2bf(a[0]); r[1] = (short)f2bf(a[1]);
  r[2] = (short)f2bf(a[2]); r[3] = (short)f2bf(a[3]);
  r[4] = (short)f2bf(b[0]); r[5] = (short)f2bf(b[1]);
  r[6] = (short)f2bf(b[2]); r[7] = (short)f2bf(b[3]);
  *(short8*)(d) = r;
}

__global__ void cvt_x(const float* __restrict__ s, u16* __restrict__ d, int n) {
  const int i = (blockIdx.x * 256 + threadIdx.x) * 8;
  if (i >= n) return;
  cvt8(s + i, d + i);
}

__global__ void cvt_w4(const float* __restrict__ w0, const float* __restrict__ w1,
                       const float* __restrict__ w2, const float* __restrict__ w3,
                       u16* __restrict__ d) {
  const int z = blockIdx.y;
  const float* s = (z == 0) ? w0 : (z == 1) ? w1 : (z == 2) ? w2 : w3;
  const int i = (blockIdx.x * 256 + threadIdx.x) * 8;
  cvt8(s + i, d + (size_t)z * 1048576 + i);
}

// one launch: y in {0,1,2} -> q,k,v (4096 blocks each); y==3 -> the 4 weight
// matrices (2048 blocks used, 512 per weight; rest exit).
__global__ void cvt_all(const float* __restrict__ q, const float* __restrict__ k,
                        const float* __restrict__ v, const float* __restrict__ w0,
                        const float* __restrict__ w1, const float* __restrict__ w2,
                        const float* __restrict__ w3, u16* __restrict__ dx,
                        u16* __restrict__ dw) {
  const int z = blockIdx.y;
  if (z < 3) {
    const float* s = (z == 0) ? q : (z == 1) ? k : v;
    const int i = (blockIdx.x * 256 + threadIdx.x) * 8;
    cvt8(s + i, dx + (size_t)z * 8388608 + i);
  } else {
    const int bi = blockIdx.x;
    if (bi >= 2048) return;
    const int w = bi >> 9;
    const float* s = (w == 0) ? w0 : (w == 1) ? w1 : (w == 2) ? w2 : w3;
    const int i = ((bi & 511) * 256 + threadIdx.x) * 8;
    cvt8(s + i, dw + (size_t)w * 1048576 + i);
  }
}

// XCD-aware tile swizzle: consecutive dispatch ids round-robin across the 8
// XCDs; remap so each XCD owns a CONTIGUOUS run of M-strips (A-panel + W
// L2-resident). Bijective iff nwg % 8 == 0 (true for all our grids).
__device__ __forceinline__ void xcd_swz(unsigned& bx, unsigned& by) {
  const unsigned nx = gridDim.x, nwg = nx * gridDim.y;
  if ((nwg & 7u) == 0u) {
    const unsigned lin = bx + nx * by;
    const unsigned swz = (lin & 7u) * (nwg >> 3) + (lin >> 3);
    bx = swz % nx;
    by = swz / nx;
  }
}

// ---------------------------------------------------------------- GEMM
// C[m][n] = (sum_k A[m][k]*W[n][k] + bias[n]) * scale; 128x128 tile, GK=32,
// dbuf staging. TRANS: write C^T[n][m] (for V^T) with packed b64 stores.
#define GM 128
#define GN 128
#define GK 32

template <typename TC, bool TRANS>
__global__ __launch_bounds__(256, 3) void gemm_bb(
    const u16* __restrict__ A, const u16* __restrict__ W,
    const float* __restrict__ bias, TC* __restrict__ C,
    int M, int N, int K, float scale)
{
  __shared__ __align__(16) u16 As[2][GM * GK];   // 16 KB
  __shared__ __align__(16) u16 Bs[2][GN * GK];   // 16 KB

  const int tid  = threadIdx.x;
  const int lane = tid & 63;
  const int l15  = lane & 15;
  const int quad = lane >> 4;
  const int wave = tid >> 6;
  unsigned bxu = blockIdx.x, byu = blockIdx.y;
  xcd_swz(bxu, byu);
  const int bm = byu * GM;
  const int bn = bxu * GN;
  const int wm = (wave >> 1) * 64;
  const int wn = (wave & 1) * 64;

  const f32x4 zero4 = {0.f, 0.f, 0.f, 0.f};
  f32x4 acc[4][4];
#pragma unroll
  for (int i = 0; i < 4; i++)
#pragma unroll
    for (int j = 0; j < 4; j++) acc[i][j] = zero4;

  const int srow = tid >> 2;
  const int chl  = (tid & 3) ^ ((tid >> 3) & 3);
  const u16* Ag = A + (size_t)(bm + srow) * K + chl * 8;
  const u16* Wg = W + (size_t)(bn + srow) * K + chl * 8;
  const size_t rowskip = (size_t)64 * K;
  const int chpA = quad ^ ((l15 >> 1) & 3);

  gll16(Ag, &As[0][tid * 8]);
  gll16(Ag + rowskip, &As[0][tid * 8 + 2048]);
  gll16(Wg, &Bs[0][tid * 8]);
  gll16(Wg + rowskip, &Bs[0][tid * 8 + 2048]);

  int buf = 0;
  for (int k0 = 0; k0 < K; k0 += GK) {
    __syncthreads();
    if (k0 + GK < K) {
      const int nb = buf ^ 1;
      gll16(Ag + k0 + GK, &As[nb][tid * 8]);
      gll16(Ag + k0 + GK + rowskip, &As[nb][tid * 8 + 2048]);
      gll16(Wg + k0 + GK, &Bs[nb][tid * 8]);
      gll16(Wg + k0 + GK + rowskip, &Bs[nb][tid * 8 + 2048]);
    }

    short8 af[4], bfr[4];
#pragma unroll
    for (int mi = 0; mi < 4; mi++)
      af[mi] = *(const short8*)&As[buf][(wm + mi * 16 + l15) * GK + chpA * 8];
#pragma unroll
    for (int ni = 0; ni < 4; ni++)
      bfr[ni] = *(const short8*)&Bs[buf][(wn + ni * 16 + l15) * GK + chpA * 8];
#pragma unroll
    for (int mi = 0; mi < 4; mi++)
#pragma unroll
      for (int ni = 0; ni < 4; ni++)
        acc[mi][ni] = __builtin_amdgcn_mfma_f32_16x16x32_bf16(
            af[mi], bfr[ni], acc[mi][ni], 0, 0, 0);
    buf ^= 1;
  }

  float bval[4];
#pragma unroll
  for (int ni = 0; ni < 4; ni++) bval[ni] = bias[bn + wn + ni * 16 + l15];
#pragma unroll
  for (int mi = 0; mi < 4; mi++) {
    const int m0 = bm + wm + mi * 16 + quad * 4;
#pragma unroll
    for (int ni = 0; ni < 4; ni++) {
      const int n = bn + wn + ni * 16 + l15;
      if constexpr (TRANS) {
        ushort4 w;
        w.x = f2bf((acc[mi][ni][0] + bval[ni]) * scale);
        w.y = f2bf((acc[mi][ni][1] + bval[ni]) * scale);
        w.z = f2bf((acc[mi][ni][2] + bval[ni]) * scale);
        w.w = f2bf((acc[mi][ni][3] + bval[ni]) * scale);
        *(ushort4*)((u16*)C + (size_t)n * M + m0) = w;
      } else {
#pragma unroll
        for (int r = 0; r < 4; r++) {
          const float v = (acc[mi][ni][r] + bval[ni]) * scale;
          if constexpr (sizeof(TC) == 2)
            C[(size_t)(m0 + r) * N + n] = f2bf(v);
          else
            C[(size_t)(m0 + r) * N + n] = v;
        }
      }
    }
  }
}

// z-batched QKV projection: z=0 -> Qb (scaled by qscale), z=1 -> Kb,
// z=2 -> V^T (transposed store). All selects are wave-uniform per block.
__global__ __launch_bounds__(256, 3) void gemm_qkv(
    const u16* __restrict__ Ab, const u16* __restrict__ Wc,
    const float* __restrict__ bq, const float* __restrict__ bk,
    const float* __restrict__ bv, u16* __restrict__ Qo,
    u16* __restrict__ Ko, u16* __restrict__ Vo, float qscale)
{
  const int M = 8192, N = 1024, K = 1024;
  const int z = blockIdx.z;
  const u16* A = Ab + (size_t)z * 8388608;
  const u16* W = Wc + (size_t)z * 1048576;
  const float* bias = (z == 0) ? bq : (z == 1) ? bk : bv;
  u16* C = (z == 0) ? Qo : (z == 1) ? Ko : Vo;
  const float scale = (z == 0) ? qscale : 1.0f;
  const bool trans = (z == 2);

  __shared__ __align__(16) u16 As[2][GM * GK];
  __shared__ __align__(16) u16 Bs[2][GN * GK];

  const int tid  = threadIdx.x;
  const int lane = tid & 63;
  const int l15  = lane & 15;
  const int quad = lane >> 4;
  const int wave = tid >> 6;
  unsigned bxu = blockIdx.x, byu = blockIdx.y;
  xcd_swz(bxu, byu);
  const int bm = byu * GM;
  const int bn = bxu * GN;
  const int wm = (wave >> 1) * 64;
  const int wn = (wave & 1) * 64;

  const f32x4 zero4 = {0.f, 0.f, 0.f, 0.f};
  f32x4 acc[4][4];
#pragma unroll
  for (int i = 0; i < 4; i++)
#pragma unroll
    for (int j = 0; j < 4; j++) acc[i][j] = zero4;

  const int srow = tid >> 2;
  const int chl  = (tid & 3) ^ ((tid >> 3) & 3);
  const u16* Ag = A + (size_t)(bm + srow) * K + chl * 8;
  const u16* Wg = W + (size_t)(bn + srow) * K + chl * 8;
  const size_t rowskip = (size_t)64 * K;
  const int chpA = quad ^ ((l15 >> 1) & 3);

  gll16(Ag, &As[0][tid * 8]);
  gll16(Ag + rowskip, &As[0][tid * 8 + 2048]);
  gll16(Wg, &Bs[0][tid * 8]);
  gll16(Wg + rowskip, &Bs[0][tid * 8 + 2048]);

  int buf = 0;
  for (int k0 = 0; k0 < K; k0 += GK) {
    __syncthreads();
    if (k0 + GK < K) {
      const int nb = buf ^ 1;
      gll16(Ag + k0 + GK, &As[nb][tid * 8]);
      gll16(Ag + k0 + GK + rowskip, &As[nb][tid * 8 + 2048]);
      gll16(Wg + k0 + GK, &Bs[nb][tid * 8]);
      gll16(Wg + k0 + GK + rowskip, &Bs[nb][tid * 8 + 2048]);
    }

    short8 af[4], bfr[4];
#pragma unroll
    for (int mi = 0; mi < 4; mi++)
      af[mi] = *(const short8*)&As[buf][(wm + mi * 16 + l15) * GK + chpA * 8];
#pragma unroll
    for (int ni = 0; ni < 4; ni++)
      bfr[ni] = *(const short8*)&Bs[buf][(wn + ni * 16 + l15) * GK + chpA * 8];
#pragma unroll
    for (int mi = 0; mi < 4; mi++)
#pragma unroll
      for (int ni = 0; ni < 4; ni++)
        acc[mi][ni] = __builtin_amdgcn_mfma_f32_16x16x32_bf16(
            af[mi], bfr[ni], acc[mi][ni], 0, 0, 0);
    buf ^= 1;
  }

  float bval[4];
#pragma unroll
  for (int ni = 0; ni < 4; ni++) bval[ni] = bias[bn + wn + ni * 16 + l15];
#pragma unroll
  for (int mi = 0; mi < 4; mi++) {
    const int m0 = bm + wm + mi * 16 + quad * 4;
#pragma unroll
    for (int ni = 0; ni < 4; ni++) {
      const int n = bn + wn + ni * 16 + l15;
      if (trans) {
        ushort4 w;
        w.x = f2bf(acc[mi][ni][0] + bval[ni]);
        w.y = f2bf(acc[mi][ni][1] + bval[ni]);
        w.z = f2bf(acc[mi][ni][2] + bval[ni]);
        w.w = f2bf(acc[mi][ni][3] + bval[ni]);
        *(ushort4*)(C + (size_t)n * M + m0) = w;
      } else {
#pragma unroll
        for (int r = 0; r < 4; r++)
          C[(size_t)(m0 + r) * N + n] = f2bf((acc[mi][ni][r] + bval[ni]) * scale);
      }
    }
  }
}

// ---------------------------------------------------------------- attention
// grid (S/128, B*H) XCD-swizzled; 4 waves x 32 q-rows; 64-key tiles; K and V
// both single-buffered (V staged during QK, K_{i+1} staged during PV);
// 2 barriers/iter; 32KB LDS -> 4 blocks/CU. Per-tile unmasked bitmap skips
// all mask work on open tiles. S^T orientation; exact softmax.
// Q arrives pre-scaled by (1/sqrt(dk))*log2(e). Math identical to round-6/8/9.
// setprio(1) wraps the MFMA clusters (m191; round-10-verified).
__global__ __launch_bounds__(256, 4) void attn_fused(
    const u16* __restrict__ Qb, const u16* __restrict__ Kb,
    const u16* __restrict__ VtG, const int* __restrict__ mask,
    u16* __restrict__ Ob)
{
  constexpr int S = 2048, D = 1024;
  __shared__ __align__(16) u16 Ks[64 * 64];      // [s][dk], 16B chunks ^(s&7), 8KB
  __shared__ __align__(16) u16 Vs[64 * 64];      // [d][s],  16B chunks ^(d&7), 8KB
  __shared__ __align__(16) u16 Pt[4][32 * 64];   // [q][k],  16B chunks ^(q&7), 16KB

  const int tid  = threadIdx.x;
  const int lane = tid & 63;
  const int wave = tid >> 6;
  const int l15  = lane & 15;
  const int quad = lane >> 4;

  // XCD swizzle: 1024 wgs; XCD c owns swz in [128c,128c+128) -> 8 (b,h) pairs
  // (K/V 8 x 0.5MB = 4MB, L2-resident) x all 16 q-blocks.
  const int lin = blockIdx.x + 16 * blockIdx.y;
  const int swz = (lin & 7) * 128 + (lin >> 3);
  const int b  = swz >> 8;
  const int h  = (swz >> 4) & 15;
  const int qw = (swz & 15) * 128 + wave * 32;

  const u16* Qp = Qb + (size_t)b * S * D + h * 64;
  const u16* Kp = Kb + (size_t)b * S * D + h * 64;
  const u16* Vg = VtG + (size_t)h * 64 * 8192 + b * 2048;  // [dim][token]
  const int* mp = mask + b * S;

  // Q fragments (B-operand of S^T = K*Q^T; same per-lane layout as A-operand)
  short8 qf[2][2];
#pragma unroll
  for (int qb = 0; qb < 2; qb++)
#pragma unroll
    for (int c = 0; c < 2; c++)
      qf[qb][c] = *(const short8*)&Qp[(size_t)(qw + qb * 16 + l15) * D + c * 32 + quad * 8];

  const f32x4 zero4 = {0.f, 0.f, 0.f, 0.f};
  f32x4 o_acc[2][4];
#pragma unroll
  for (int qb = 0; qb < 2; qb++)
#pragma unroll
    for (int ni = 0; ni < 4; ni++) o_acc[qb][ni] = zero4;
  f32x4 l_acc[2] = {zero4, zero4};   // row-sums via ones-MFMA (same C-layout as o_acc)

  const short8 one8 = {(short)0x3f80, (short)0x3f80, (short)0x3f80, (short)0x3f80,
                       (short)0x3f80, (short)0x3f80, (short)0x3f80, (short)0x3f80};

  // staging (round-4 verified): phys chunk tid&7 of row p*32+(tid>>3),
  // logical = phys ^ (row&7), swizzle applied on the GLOBAL column.
  const int srow = tid >> 3;
  const int chl  = (tid & 7) ^ (srow & 7);
  const int fsw  = l15 & 7;

  // ---- per-64-key-tile "fully unmasked" bitmap (32 tiles). tbs aliases the
  // first 16B of Pt: read into registers (post-sync) strictly before any Pt
  // write (which only happens after the loop-top barrier).
  unsigned int* tbs = (unsigned int*)&Pt[0][0];
  {
    const int t8 = tid * 8;                    // 256 threads x 8 ints = 2048
    int4 a  = *(const int4*)&mp[t8];
    int4 c4 = *(const int4*)&mp[t8 + 4];
    int ok = ((a.x & a.y & a.z & a.w & c4.x & c4.y & c4.z & c4.w) != 0);
    unsigned long long bb = __ballot(ok);      // lane i covers tile w*8+(i>>3)
    if (lane == 0) {
      unsigned int byt = 0;
#pragma unroll
      for (int g = 0; g < 8; g++)
        if (((bb >> (8 * g)) & 0xffull) == 0xffull) byt |= 1u << g;
      tbs[wave] = byt;
    }
  }

  // pre-loop: stage K_0
#pragma unroll
  for (int p = 0; p < 2; p++)
    gll16(Kp + (size_t)(p * 32 + srow) * D + chl * 8, &Ks[p * 2048 + tid * 8]);

  __syncthreads();
  const unsigned int tilebits = __builtin_amdgcn_readfirstlane(
      tbs[0] | (tbs[1] << 8) | (tbs[2] << 16) | (tbs[3] << 24));

  for (int kt = 0; kt < S; kt += 64) {
    __syncthreads();   // A: K_kt landed (staged post-B of prev iter / prologue);
                       //    Vs + Pt free (prev PV reads done).

    // stage V_kt (drained at barrier B, overlapped with QK+softmax)
#pragma unroll
    for (int p = 0; p < 2; p++)
      gll16(Vg + (size_t)(p * 32 + srow) * 8192 + kt + chl * 8,
            &Vs[p * 2048 + tid * 8]);

    // ---- S^T = K Q^T : sc[qb][s], rows=keys s*16+quad*4+r, col q=l15
    f32x4 sc[2][4];
#pragma unroll
    for (int qb = 0; qb < 2; qb++)
#pragma unroll
      for (int s = 0; s < 4; s++) sc[qb][s] = zero4;
    __builtin_amdgcn_s_setprio(1);
#pragma unroll
    for (int c = 0; c < 2; c++)
#pragma unroll
      for (int s = 0; s < 4; s++) {
        short8 kf = *(const short8*)
            &Ks[(s * 16 + l15) * 64 + ((c * 4 + quad) ^ fsw) * 8];
        sc[0][s] = __builtin_amdgcn_mfma_f32_16x16x32_bf16(kf, qf[0][c], sc[0][s], 0, 0, 0);
        sc[1][s] = __builtin_amdgcn_mfma_f32_16x16x32_bf16(kf, qf[1][c], sc[1][s], 0, 0, 0);
      }
    __builtin_amdgcn_s_setprio(0);

    // ---- P^T = exp2(sc [+ mask]); truncate+pack 2 keys per v_perm_b32
    const bool open = (tilebits >> (kt >> 6)) & 1;   // wave-uniform (sgpr)
    if (open) {
#pragma unroll
      for (int qb = 0; qb < 2; qb++) {
        const int qrow = qb * 16 + l15;
#pragma unroll
        for (int s = 0; s < 4; s++) {
          unsigned int t[4];
#pragma unroll
          for (int r = 0; r < 4; r++) {
            union { float f; unsigned int u; } pu;
            pu.f = __builtin_amdgcn_exp2f(sc[qb][s][r]);
            t[r] = pu.u;
          }
          uint2 w;
          w.x = __builtin_amdgcn_perm(t[1], t[0], 0x07060302u);  // keys +0,+1
          w.y = __builtin_amdgcn_perm(t[3], t[2], 0x07060302u);  // keys +2,+3
          const int phys = (s * 2 + (quad >> 1)) ^ fsw;
          *(uint2*)&Pt[wave][qrow * 64 + phys * 8 + (quad & 1) * 4] = w;
        }
      }
    } else {
      f32x4 cm[4];
#pragma unroll
      for (int s = 0; s < 4; s++) {
        int4 mv = *(const int4*)&mp[kt + s * 16 + quad * 4];
        cm[s][0] = mv.x ? 0.f : -1.0e9f;
        cm[s][1] = mv.y ? 0.f : -1.0e9f;
        cm[s][2] = mv.z ? 0.f : -1.0e9f;
        cm[s][3] = mv.w ? 0.f : -1.0e9f;
      }
#pragma unroll
      for (int qb = 0; qb < 2; qb++) {
        const int qrow = qb * 16 + l15;
#pragma unroll
        for (int s = 0; s < 4; s++) {
          unsigned int t[4];
#pragma unroll
          for (int r = 0; r < 4; r++) {
            union { float f; unsigned int u; } pu;
            pu.f = __builtin_amdgcn_exp2f(sc[qb][s][r] + cm[s][r]);
            t[r] = pu.u;
          }
          uint2 w;
          w.x = __builtin_amdgcn_perm(t[1], t[0], 0x07060302u);
          w.y = __builtin_amdgcn_perm(t[3], t[2], 0x07060302u);
          const int phys = (s * 2 + (quad >> 1)) ^ fsw;
          *(uint2*)&Pt[wave][qrow * 64 + phys * 8 + (quad & 1) * 4] = w;
        }
      }
    }

    __syncthreads();   // B: V_kt landed; all waves' QK reads of Ks done.

    // stage K_{kt+64} into Ks (safe post-B; drained at next barrier A),
    // overlapped with PV below.
    if (kt + 64 < S) {
#pragma unroll
      for (int p = 0; p < 2; p++)
        gll16(Kp + (size_t)(kt + 64 + p * 32 + srow) * D + chl * 8,
              &Ks[p * 2048 + tid * 8]);
    }

    // ---- O += P V ; l += P 1  (A = pf from Pt rows; same-wave Pt
    //      write->read, DS in-order per wave)
    __builtin_amdgcn_s_setprio(1);
#pragma unroll
    for (int c = 0; c < 2; c++) {
      short8 pf[2];
#pragma unroll
      for (int qb = 0; qb < 2; qb++)
        pf[qb] = *(const short8*)
            &Pt[wave][(qb * 16 + l15) * 64 + ((c * 4 + quad) ^ fsw) * 8];
      l_acc[0] = __builtin_amdgcn_mfma_f32_16x16x32_bf16(pf[0], one8, l_acc[0], 0, 0, 0);
      l_acc[1] = __builtin_amdgcn_mfma_f32_16x16x32_bf16(pf[1], one8, l_acc[1], 0, 0, 0);
#pragma unroll
      for (int ni = 0; ni < 4; ni++) {
        short8 vf = *(const short8*)
            &Vs[(ni * 16 + l15) * 64 + ((c * 4 + quad) ^ fsw) * 8];
        o_acc[0][ni] = __builtin_amdgcn_mfma_f32_16x16x32_bf16(pf[0], vf, o_acc[0][ni], 0, 0, 0);
        o_acc[1][ni] = __builtin_amdgcn_mfma_f32_16x16x32_bf16(pf[1], vf, o_acc[1][ni], 0, 0, 0);
      }
    }
    __builtin_amdgcn_s_setprio(0);
  }

  // ---- epilogue: l_acc reg r holds l for q-row qb*16+quad*4+r — exactly
  //      the o_acc row layout; no cross-lane reduction needed.
  float rl[2][4];
#pragma unroll
  for (int qb = 0; qb < 2; qb++)
#pragma unroll
    for (int r = 0; r < 4; r++) rl[qb][r] = 1.0f / l_acc[qb][r];
#pragma unroll
  for (int qb = 0; qb < 2; qb++) {
    const int q0 = qw + qb * 16 + quad * 4;
#pragma unroll
    for (int ni = 0; ni < 4; ni++)
#pragma unroll
      for (int r = 0; r < 4; r++)
        Ob[(size_t)(b * S + q0 + r) * D + h * 64 + ni * 16 + l15] =
            f2bf(o_acc[qb][ni][r] * rl[qb][r]);
  }
}

// ---------------------------------------------------------------- launch
extern "C" void kernel_launch(void* const* d_in, const int* in_sizes, int n_in,
                              void* d_out, int out_size, void* d_ws, size_t ws_size,
                              hipStream_t stream) {
  const int M = 8192, N = 1024, K = 1024;
  const float* q    = (const float*)d_in[0];
  const float* k    = (const float*)d_in[1];
  const float* v    = (const float*)d_in[2];
  const int*   mask = (const int*)d_in[3];
  const float* Wq = (const float*)d_in[4];
  const float* bq = (const float*)d_in[5];
  const float* Wk = (const float*)d_in[6];
  const float* bk = (const float*)d_in[7];
  const float* Wv = (const float*)d_in[8];
  const float* bv = (const float*)d_in[9];
  const float* Wo = (const float*)d_in[10];
  const float* bo = (const float*)d_in[11];

  const size_t MN = (size_t)M * N;                  // 8388608
  const float QSC = 0.125f * 1.44269504f;           // (1/sqrt(dk)) * log2(e)

  dim3 bb(256);
  dim3 gg(N / GN, M / GM);

  const size_t need_batched = (6 * MN + 4 * 1048576) * sizeof(u16);  // ~109 MB
  if (ws_size >= need_batched) {
    u16* Ax  = (u16*)d_ws;            // 3*MN: q,k,v bf16 (reused as Ob later)
    u16* Qb  = Ax + 3 * MN;
    u16* Kb  = Ax + 4 * MN;
    u16* VtG = Ax + 5 * MN;           // V^T: [1024 dims][8192 tokens]
    u16* Wc  = Ax + 6 * MN;           // 4 x 1M bf16 weights
    u16* Ob  = Ax;                    // attn output (QKV gemms done reading)

    cvt_all<<<dim3(4096, 4), bb, 0, stream>>>(q, k, v, Wq, Wk, Wv, Wo, Ax, Wc);
    gemm_qkv<<<dim3(8, 64, 3), bb, 0, stream>>>(Ax, Wc, bq, bk, bv, Qb, Kb, VtG, QSC);
    attn_fused<<<dim3(16, 64), bb, 0, stream>>>(Qb, Kb, VtG, mask, Ob);
    gemm_bb<float, false><<<gg, bb, 0, stream>>>(Ob, Wc + 3 * 1048576, bo,
                                                 (float*)d_out, M, N, K, 1.0f);
  } else {
    // sequential fallback (round-5 layout, 75.5 MB)
    u16* Qb  = (u16*)d_ws;
    u16* Kb  = Qb + MN;
    u16* VtG = Kb + MN;
    u16* Ob  = VtG + MN;
    u16* Wc  = Ob + MN;
    const int xblk = (int)(MN / (256 * 8));

    cvt_w4<<<dim3(512, 4), bb, 0, stream>>>(Wq, Wk, Wv, Wo, Wc);

    cvt_x<<<xblk, bb, 0, stream>>>(q, Ob, M * N);
    gemm_bb<u16, false><<<gg, bb, 0, stream>>>(Ob, Wc + 0 * 1048576, bq, Qb, M, N, K, QSC);
    cvt_x<<<xblk, bb, 0, stream>>>(k, Ob, M * N);
    gemm_bb<u16, false><<<gg, bb, 0, stream>>>(Ob, Wc + 1 * 1048576, bk, Kb, M, N, K, 1.0f);
    cvt_x<<<xblk, bb, 0, stream>>>(v, Ob, M * N);
    gemm_bb<u16, true><<<gg, bb, 0, stream>>>(Ob, Wc + 2 * 1048576, bv, VtG, M, N, K, 1.0f);

    attn_fused<<<dim3(16, 64), bb, 0, stream>>>(Qb, Kb, VtG, mask, Ob);

    gemm_bb<float, false><<<gg, bb, 0, stream>>>(Ob, Wc + 3 * 1048576, bo,
                                                 (float*)d_out, M, N, K, 1.0f);
  }
}

// Round 8
// 334.285 us; speedup vs baseline: 1.0543x; 1.0075x over previous
//
#include <hip/hip_runtime.h>

// MultiHeadAttention: B=4, S=2048, D=1024, H=16, dk=64. fp32 I/O, bf16 internal.
//
// Round-13 = round-12 resubmitted verbatim (round-12 bench was an infra
// failure: "MI355X container failed twice" — no pytest, no counters; kernel
// never evaluated. gemm_qkv2 re-audited: swizzle algebra, bounds, occupancy
// all verified; no hang risk found).
//
// Round-12 (round-11 counters: attn 86.3us with FETCH 26.7MB (swizzle works,
// MFMA-floor ~37us -> limited headroom); gemm_qkv ~86us with 6-blocks/CU work
// on 5-resident = ragged tail + only ~12-20 waves/CU hiding the barrier
// drain):
//   - gemm_qkv RETILED to 256x128, 512 threads (8 waves x 64x64), GK=32:
//     grid (8,32,3)=768 = EXACTLY 3 blocks/CU, LDS 48KB = exactly 3 resident
//     -> zero tail, 24 waves/CU, 2x MFMA per barrier, 3 gll16/thread/iter.
//     Inner fragment math / MFMA order / epilogue byte-identical (same
//     accumulation order -> absmax bit-identical). Staging XOR algebra
//     verified for the +128-row half (128>>1 = 64 = 0 mod 4).
//   - cvt_all reverted to cvt_w4 + cvt_x3 (merge measured ~-2us, no benefit).
//   - attn/gemm_bb unchanged from round-11 (attn keeps setprio).

typedef unsigned short u16;
typedef __attribute__((ext_vector_type(8))) short short8;   // 8 bf16 = 4 VGPRs
typedef __attribute__((ext_vector_type(4))) float f32x4;

__device__ __forceinline__ u16 f2bf(float f) {               // RNE (epilogues)
  union { float f; unsigned int u; } v; v.f = f;
  return (u16)((v.u + 0x7FFFu + ((v.u >> 16) & 1u)) >> 16);
}

__device__ __forceinline__ void gll16(const void* gptr, void* lptr) {
  __builtin_amdgcn_global_load_lds(
      (const __attribute__((address_space(1))) unsigned int*)gptr,
      (__attribute__((address_space(3))) unsigned int*)lptr, 16, 0, 0);
}

// ---------------------------------------------------------------- converts
__device__ __forceinline__ void cvt8(const float* __restrict__ s,
                                     u16* __restrict__ d) {
  f32x4 a = *(const f32x4*)(s);
  f32x4 b = *(const f32x4*)(s + 4);
  short8 r;
  r[0] = (short)f2bf(a[0]); r[1] = (short)f2bf(a[1]);
  r[2] = (short)f2bf(a[2]); r[3] = (short)f2bf(a[3]);
  r[4] = (short)f2bf(b[0]); r[5] = (short)f2bf(b[1]);
  r[6] = (short)f2bf(b[2]); r[7] = (short)f2bf(b[3]);
  *(short8*)(d) = r;
}

__global__ void cvt_x(const float* __restrict__ s, u16* __restrict__ d, int n) {
  const int i = (blockIdx.x * 256 + threadIdx.x) * 8;
  if (i >= n) return;
  cvt8(s + i, d + i);
}

__global__ void cvt_x3(const float* __restrict__ q, const float* __restrict__ k,
                       const float* __restrict__ v, u16* __restrict__ d) {
  const int z = blockIdx.y;
  const float* s = (z == 0) ? q : (z == 1) ? k : v;
  const int i = (blockIdx.x * 256 + threadIdx.x) * 8;
  cvt8(s + i, d + (size_t)z * 8388608 + i);
}

__global__ void cvt_w4(const float* __restrict__ w0, const float* __restrict__ w1,
                       const float* __restrict__ w2, const float* __restrict__ w3,
                       u16* __restrict__ d) {
  const int z = blockIdx.y;
  const float* s = (z == 0) ? w0 : (z == 1) ? w1 : (z == 2) ? w2 : w3;
  const int i = (blockIdx.x * 256 + threadIdx.x) * 8;
  cvt8(s + i, d + (size_t)z * 1048576 + i);
}

// XCD-aware tile swizzle: consecutive dispatch ids round-robin across the 8
// XCDs; remap so each XCD owns a CONTIGUOUS run of M-strips (A-panel + W
// L2-resident). Bijective iff nwg % 8 == 0 (true for all our grids).
__device__ __forceinline__ void xcd_swz(unsigned& bx, unsigned& by) {
  const unsigned nx = gridDim.x, nwg = nx * gridDim.y;
  if ((nwg & 7u) == 0u) {
    const unsigned lin = bx + nx * by;
    const unsigned swz = (lin & 7u) * (nwg >> 3) + (lin >> 3);
    bx = swz % nx;
    by = swz / nx;
  }
}

// ---------------------------------------------------------------- GEMM
// C[m][n] = (sum_k A[m][k]*W[n][k] + bias[n]) * scale; 128x128 tile, GK=32,
// dbuf staging. TRANS: write C^T[n][m] (for V^T) with packed b64 stores.
#define GM 128
#define GN 128
#define GK 32

template <typename TC, bool TRANS>
__global__ __launch_bounds__(256, 3) void gemm_bb(
    const u16* __restrict__ A, const u16* __restrict__ W,
    const float* __restrict__ bias, TC* __restrict__ C,
    int M, int N, int K, float scale)
{
  __shared__ __align__(16) u16 As[2][GM * GK];   // 16 KB
  __shared__ __align__(16) u16 Bs[2][GN * GK];   // 16 KB

  const int tid  = threadIdx.x;
  const int lane = tid & 63;
  const int l15  = lane & 15;
  const int quad = lane >> 4;
  const int wave = tid >> 6;
  unsigned bxu = blockIdx.x, byu = blockIdx.y;
  xcd_swz(bxu, byu);
  const int bm = byu * GM;
  const int bn = bxu * GN;
  const int wm = (wave >> 1) * 64;
  const int wn = (wave & 1) * 64;

  const f32x4 zero4 = {0.f, 0.f, 0.f, 0.f};
  f32x4 acc[4][4];
#pragma unroll
  for (int i = 0; i < 4; i++)
#pragma unroll
    for (int j = 0; j < 4; j++) acc[i][j] = zero4;

  const int srow = tid >> 2;
  const int chl  = (tid & 3) ^ ((tid >> 3) & 3);
  const u16* Ag = A + (size_t)(bm + srow) * K + chl * 8;
  const u16* Wg = W + (size_t)(bn + srow) * K + chl * 8;
  const size_t rowskip = (size_t)64 * K;
  const int chpA = quad ^ ((l15 >> 1) & 3);

  gll16(Ag, &As[0][tid * 8]);
  gll16(Ag + rowskip, &As[0][tid * 8 + 2048]);
  gll16(Wg, &Bs[0][tid * 8]);
  gll16(Wg + rowskip, &Bs[0][tid * 8 + 2048]);

  int buf = 0;
  for (int k0 = 0; k0 < K; k0 += GK) {
    __syncthreads();
    if (k0 + GK < K) {
      const int nb = buf ^ 1;
      gll16(Ag + k0 + GK, &As[nb][tid * 8]);
      gll16(Ag + k0 + GK + rowskip, &As[nb][tid * 8 + 2048]);
      gll16(Wg + k0 + GK, &Bs[nb][tid * 8]);
      gll16(Wg + k0 + GK + rowskip, &Bs[nb][tid * 8 + 2048]);
    }

    short8 af[4], bfr[4];
#pragma unroll
    for (int mi = 0; mi < 4; mi++)
      af[mi] = *(const short8*)&As[buf][(wm + mi * 16 + l15) * GK + chpA * 8];
#pragma unroll
    for (int ni = 0; ni < 4; ni++)
      bfr[ni] = *(const short8*)&Bs[buf][(wn + ni * 16 + l15) * GK + chpA * 8];
#pragma unroll
    for (int mi = 0; mi < 4; mi++)
#pragma unroll
      for (int ni = 0; ni < 4; ni++)
        acc[mi][ni] = __builtin_amdgcn_mfma_f32_16x16x32_bf16(
            af[mi], bfr[ni], acc[mi][ni], 0, 0, 0);
    buf ^= 1;
  }

  float bval[4];
#pragma unroll
  for (int ni = 0; ni < 4; ni++) bval[ni] = bias[bn + wn + ni * 16 + l15];
#pragma unroll
  for (int mi = 0; mi < 4; mi++) {
    const int m0 = bm + wm + mi * 16 + quad * 4;
#pragma unroll
    for (int ni = 0; ni < 4; ni++) {
      const int n = bn + wn + ni * 16 + l15;
      if constexpr (TRANS) {
        ushort4 w;
        w.x = f2bf((acc[mi][ni][0] + bval[ni]) * scale);
        w.y = f2bf((acc[mi][ni][1] + bval[ni]) * scale);
        w.z = f2bf((acc[mi][ni][2] + bval[ni]) * scale);
        w.w = f2bf((acc[mi][ni][3] + bval[ni]) * scale);
        *(ushort4*)((u16*)C + (size_t)n * M + m0) = w;
      } else {
#pragma unroll
        for (int r = 0; r < 4; r++) {
          const float v = (acc[mi][ni][r] + bval[ni]) * scale;
          if constexpr (sizeof(TC) == 2)
            C[(size_t)(m0 + r) * N + n] = f2bf(v);
          else
            C[(size_t)(m0 + r) * N + n] = v;
        }
      }
    }
  }
}

// z-batched QKV projection, 256x128 tile, 512 threads (8 waves of 64x64).
// grid (8,32,3) = 768 blocks = exactly 3/CU; LDS 48KB = exactly 3 resident
// -> zero tail, 24 waves/CU. Inner math identical to gemm_bb (same fragment
// layouts, same MFMA order, same accumulation order -> bit-identical output).
#define HM 256
#define HN 128

__global__ __launch_bounds__(512, 4) void gemm_qkv2(
    const u16* __restrict__ Ab, const u16* __restrict__ Wc,
    const float* __restrict__ bq, const float* __restrict__ bk,
    const float* __restrict__ bv, u16* __restrict__ Qo,
    u16* __restrict__ Ko, u16* __restrict__ Vo, float qscale)
{
  const int M = 8192, N = 1024, K = 1024;
  const int z = blockIdx.z;
  const u16* A = Ab + (size_t)z * 8388608;
  const u16* W = Wc + (size_t)z * 1048576;
  const float* bias = (z == 0) ? bq : (z == 1) ? bk : bv;
  u16* C = (z == 0) ? Qo : (z == 1) ? Ko : Vo;
  const float scale = (z == 0) ? qscale : 1.0f;
  const bool trans = (z == 2);

  __shared__ __align__(16) u16 As[2][HM * GK];   // 2 x 16 KB
  __shared__ __align__(16) u16 Bs[2][HN * GK];   // 2 x  8 KB

  const int tid  = threadIdx.x;
  const int lane = tid & 63;
  const int l15  = lane & 15;
  const int quad = lane >> 4;
  const int wave = tid >> 6;            // 0..7
  unsigned bxu = blockIdx.x, byu = blockIdx.y;
  xcd_swz(bxu, byu);
  const int bm = byu * HM;
  const int bn = bxu * HN;
  const int wm = (wave >> 1) * 64;      // 0,64,128,192
  const int wn = (wave & 1) * 64;       // 0,64

  const f32x4 zero4 = {0.f, 0.f, 0.f, 0.f};
  f32x4 acc[4][4];
#pragma unroll
  for (int i = 0; i < 4; i++)
#pragma unroll
    for (int j = 0; j < 4; j++) acc[i][j] = zero4;

  // staging: 512 threads; A-tile 256x32 (2 gll16/thread, halves 128 rows
  // apart), B-tile 128x32 (1 gll16/thread). Same XOR swizzle algebra as
  // gemm_bb: write key (srow>>1)&3 == read key (l15>>1)&3 for both A halves
  // (row+128 -> key unchanged since 128>>1 = 64 = 0 mod 4).
  const int srow = tid >> 2;            // 0..127
  const int chl  = (tid & 3) ^ ((tid >> 3) & 3);
  const u16* Ag = A + (size_t)(bm + srow) * K + chl * 8;
  const u16* Wg = W + (size_t)(bn + srow) * K + chl * 8;
  const size_t rowskipA = (size_t)128 * K;
  const int chpA = quad ^ ((l15 >> 1) & 3);

  gll16(Ag, &As[0][tid * 8]);
  gll16(Ag + rowskipA, &As[0][tid * 8 + 4096]);
  gll16(Wg, &Bs[0][tid * 8]);

  int buf = 0;
  for (int k0 = 0; k0 < K; k0 += GK) {
    __syncthreads();
    if (k0 + GK < K) {
      const int nb = buf ^ 1;
      gll16(Ag + k0 + GK, &As[nb][tid * 8]);
      gll16(Ag + k0 + GK + rowskipA, &As[nb][tid * 8 + 4096]);
      gll16(Wg + k0 + GK, &Bs[nb][tid * 8]);
    }

    short8 af[4], bfr[4];
#pragma unroll
    for (int mi = 0; mi < 4; mi++)
      af[mi] = *(const short8*)&As[buf][(wm + mi * 16 + l15) * GK + chpA * 8];
#pragma unroll
    for (int ni = 0; ni < 4; ni++)
      bfr[ni] = *(const short8*)&Bs[buf][(wn + ni * 16 + l15) * GK + chpA * 8];
#pragma unroll
    for (int mi = 0; mi < 4; mi++)
#pragma unroll
      for (int ni = 0; ni < 4; ni++)
        acc[mi][ni] = __builtin_amdgcn_mfma_f32_16x16x32_bf16(
            af[mi], bfr[ni], acc[mi][ni], 0, 0, 0);
    buf ^= 1;
  }

  float bval[4];
#pragma unroll
  for (int ni = 0; ni < 4; ni++) bval[ni] = bias[bn + wn + ni * 16 + l15];
#pragma unroll
  for (int mi = 0; mi < 4; mi++) {
    const int m0 = bm + wm + mi * 16 + quad * 4;
#pragma unroll
    for (int ni = 0; ni < 4; ni++) {
      const int n = bn + wn + ni * 16 + l15;
      if (trans) {
        ushort4 w;
        w.x = f2bf(acc[mi][ni][0] + bval[ni]);
        w.y = f2bf(acc[mi][ni][1] + bval[ni]);
        w.z = f2bf(acc[mi][ni][2] + bval[ni]);
        w.w = f2bf(acc[mi][ni][3] + bval[ni]);
        *(ushort4*)(C + (size_t)n * M + m0) = w;
      } else {
#pragma unroll
        for (int r = 0; r < 4; r++)
          C[(size_t)(m0 + r) * N + n] = f2bf((acc[mi][ni][r] + bval[ni]) * scale);
      }
    }
  }
}

// ---------------------------------------------------------------- attention
// grid (S/128, B*H) XCD-swizzled; 4 waves x 32 q-rows; 64-key tiles; K and V
// both single-buffered (V staged during QK, K_{i+1} staged during PV);
// 2 barriers/iter; 32KB LDS -> 4 blocks/CU. Per-tile unmasked bitmap skips
// all mask work on open tiles. S^T orientation; exact softmax.
// Q arrives pre-scaled by (1/sqrt(dk))*log2(e). Math identical to round-6/8/9.
// setprio(1) wraps the MFMA clusters (m191; round-10/11-verified).
__global__ __launch_bounds__(256, 4) void attn_fused(
    const u16* __restrict__ Qb, const u16* __restrict__ Kb,
    const u16* __restrict__ VtG, const int* __restrict__ mask,
    u16* __restrict__ Ob)
{
  constexpr int S = 2048, D = 1024;
  __shared__ __align__(16) u16 Ks[64 * 64];      // [s][dk], 16B chunks ^(s&7), 8KB
  __shared__ __align__(16) u16 Vs[64 * 64];      // [d][s],  16B chunks ^(d&7), 8KB
  __shared__ __align__(16) u16 Pt[4][32 * 64];   // [q][k],  16B chunks ^(q&7), 16KB

  const int tid  = threadIdx.x;
  const int lane = tid & 63;
  const int wave = tid >> 6;
  const int l15  = lane & 15;
  const int quad = lane >> 4;

  // XCD swizzle: 1024 wgs; XCD c owns swz in [128c,128c+128) -> 8 (b,h) pairs
  // (K/V 8 x 0.5MB = 4MB, L2-resident) x all 16 q-blocks.
  const int lin = blockIdx.x + 16 * blockIdx.y;
  const int swz = (lin & 7) * 128 + (lin >> 3);
  const int b  = swz >> 8;
  const int h  = (swz >> 4) & 15;
  const int qw = (swz & 15) * 128 + wave * 32;

  const u16* Qp = Qb + (size_t)b * S * D + h * 64;
  const u16* Kp = Kb + (size_t)b * S * D + h * 64;
  const u16* Vg = VtG + (size_t)h * 64 * 8192 + b * 2048;  // [dim][token]
  const int* mp = mask + b * S;

  // Q fragments (B-operand of S^T = K*Q^T; same per-lane layout as A-operand)
  short8 qf[2][2];
#pragma unroll
  for (int qb = 0; qb < 2; qb++)
#pragma unroll
    for (int c = 0; c < 2; c++)
      qf[qb][c] = *(const short8*)&Qp[(size_t)(qw + qb * 16 + l15) * D + c * 32 + quad * 8];

  const f32x4 zero4 = {0.f, 0.f, 0.f, 0.f};
  f32x4 o_acc[2][4];
#pragma unroll
  for (int qb = 0; qb < 2; qb++)
#pragma unroll
    for (int ni = 0; ni < 4; ni++) o_acc[qb][ni] = zero4;
  f32x4 l_acc[2] = {zero4, zero4};   // row-sums via ones-MFMA (same C-layout as o_acc)

  const short8 one8 = {(short)0x3f80, (short)0x3f80, (short)0x3f80, (short)0x3f80,
                       (short)0x3f80, (short)0x3f80, (short)0x3f80, (short)0x3f80};

  // staging (round-4 verified): phys chunk tid&7 of row p*32+(tid>>3),
  // logical = phys ^ (row&7), swizzle applied on the GLOBAL column.
  const int srow = tid >> 3;
  const int chl  = (tid & 7) ^ (srow & 7);
  const int fsw  = l15 & 7;

  // ---- per-64-key-tile "fully unmasked" bitmap (32 tiles). tbs aliases the
  // first 16B of Pt: read into registers (post-sync) strictly before any Pt
  // write (which only happens after the loop-top barrier).
  unsigned int* tbs = (unsigned int*)&Pt[0][0];
  {
    const int t8 = tid * 8;                    // 256 threads x 8 ints = 2048
    int4 a  = *(const int4*)&mp[t8];
    int4 c4 = *(const int4*)&mp[t8 + 4];
    int ok = ((a.x & a.y & a.z & a.w & c4.x & c4.y & c4.z & c4.w) != 0);
    unsigned long long bb = __ballot(ok);      // lane i covers tile w*8+(i>>3)
    if (lane == 0) {
      unsigned int byt = 0;
#pragma unroll
      for (int g = 0; g < 8; g++)
        if (((bb >> (8 * g)) & 0xffull) == 0xffull) byt |= 1u << g;
      tbs[wave] = byt;
    }
  }

  // pre-loop: stage K_0
#pragma unroll
  for (int p = 0; p < 2; p++)
    gll16(Kp + (size_t)(p * 32 + srow) * D + chl * 8, &Ks[p * 2048 + tid * 8]);

  __syncthreads();
  const unsigned int tilebits = __builtin_amdgcn_readfirstlane(
      tbs[0] | (tbs[1] << 8) | (tbs[2] << 16) | (tbs[3] << 24));

  for (int kt = 0; kt < S; kt += 64) {
    __syncthreads();   // A: K_kt landed (staged post-B of prev iter / prologue);
                       //    Vs + Pt free (prev PV reads done).

    // stage V_kt (drained at barrier B, overlapped with QK+softmax)
#pragma unroll
    for (int p = 0; p < 2; p++)
      gll16(Vg + (size_t)(p * 32 + srow) * 8192 + kt + chl * 8,
            &Vs[p * 2048 + tid * 8]);

    // ---- S^T = K Q^T : sc[qb][s], rows=keys s*16+quad*4+r, col q=l15
    f32x4 sc[2][4];
#pragma unroll
    for (int qb = 0; qb < 2; qb++)
#pragma unroll
      for (int s = 0; s < 4; s++) sc[qb][s] = zero4;
    __builtin_amdgcn_s_setprio(1);
#pragma unroll
    for (int c = 0; c < 2; c++)
#pragma unroll
      for (int s = 0; s < 4; s++) {
        short8 kf = *(const short8*)
            &Ks[(s * 16 + l15) * 64 + ((c * 4 + quad) ^ fsw) * 8];
        sc[0][s] = __builtin_amdgcn_mfma_f32_16x16x32_bf16(kf, qf[0][c], sc[0][s], 0, 0, 0);
        sc[1][s] = __builtin_amdgcn_mfma_f32_16x16x32_bf16(kf, qf[1][c], sc[1][s], 0, 0, 0);
      }
    __builtin_amdgcn_s_setprio(0);

    // ---- P^T = exp2(sc [+ mask]); truncate+pack 2 keys per v_perm_b32
    const bool open = (tilebits >> (kt >> 6)) & 1;   // wave-uniform (sgpr)
    if (open) {
#pragma unroll
      for (int qb = 0; qb < 2; qb++) {
        const int qrow = qb * 16 + l15;
#pragma unroll
        for (int s = 0; s < 4; s++) {
          unsigned int t[4];
#pragma unroll
          for (int r = 0; r < 4; r++) {
            union { float f; unsigned int u; } pu;
            pu.f = __builtin_amdgcn_exp2f(sc[qb][s][r]);
            t[r] = pu.u;
          }
          uint2 w;
          w.x = __builtin_amdgcn_perm(t[1], t[0], 0x07060302u);  // keys +0,+1
          w.y = __builtin_amdgcn_perm(t[3], t[2], 0x07060302u);  // keys +2,+3
          const int phys = (s * 2 + (quad >> 1)) ^ fsw;
          *(uint2*)&Pt[wave][qrow * 64 + phys * 8 + (quad & 1) * 4] = w;
        }
      }
    } else {
      f32x4 cm[4];
#pragma unroll
      for (int s = 0; s < 4; s++) {
        int4 mv = *(const int4*)&mp[kt + s * 16 + quad * 4];
        cm[s][0] = mv.x ? 0.f : -1.0e9f;
        cm[s][1] = mv.y ? 0.f : -1.0e9f;
        cm[s][2] = mv.z ? 0.f : -1.0e9f;
        cm[s][3] = mv.w ? 0.f : -1.0e9f;
      }
#pragma unroll
      for (int qb = 0; qb < 2; qb++) {
        const int qrow = qb * 16 + l15;
#pragma unroll
        for (int s = 0; s < 4; s++) {
          unsigned int t[4];
#pragma unroll
          for (int r = 0; r < 4; r++) {
            union { float f; unsigned int u; } pu;
            pu.f = __builtin_amdgcn_exp2f(sc[qb][s][r] + cm[s][r]);
            t[r] = pu.u;
          }
          uint2 w;
          w.x = __builtin_amdgcn_perm(t[1], t[0], 0x07060302u);
          w.y = __builtin_amdgcn_perm(t[3], t[2], 0x07060302u);
          const int phys = (s * 2 + (quad >> 1)) ^ fsw;
          *(uint2*)&Pt[wave][qrow * 64 + phys * 8 + (quad & 1) * 4] = w;
        }
      }
    }

    __syncthreads();   // B: V_kt landed; all waves' QK reads of Ks done.

    // stage K_{kt+64} into Ks (safe post-B; drained at next barrier A),
    // overlapped with PV below.
    if (kt + 64 < S) {
#pragma unroll
      for (int p = 0; p < 2; p++)
        gll16(Kp + (size_t)(kt + 64 + p * 32 + srow) * D + chl * 8,
              &Ks[p * 2048 + tid * 8]);
    }

    // ---- O += P V ; l += P 1  (A = pf from Pt rows; same-wave Pt
    //      write->read, DS in-order per wave)
    __builtin_amdgcn_s_setprio(1);
#pragma unroll
    for (int c = 0; c < 2; c++) {
      short8 pf[2];
#pragma unroll
      for (int qb = 0; qb < 2; qb++)
        pf[qb] = *(const short8*)
            &Pt[wave][(qb * 16 + l15) * 64 + ((c * 4 + quad) ^ fsw) * 8];
      l_acc[0] = __builtin_amdgcn_mfma_f32_16x16x32_bf16(pf[0], one8, l_acc[0], 0, 0, 0);
      l_acc[1] = __builtin_amdgcn_mfma_f32_16x16x32_bf16(pf[1], one8, l_acc[1], 0, 0, 0);
#pragma unroll
      for (int ni = 0; ni < 4; ni++) {
        short8 vf = *(const short8*)
            &Vs[(ni * 16 + l15) * 64 + ((c * 4 + quad) ^ fsw) * 8];
        o_acc[0][ni] = __builtin_amdgcn_mfma_f32_16x16x32_bf16(pf[0], vf, o_acc[0][ni], 0, 0, 0);
        o_acc[1][ni] = __builtin_amdgcn_mfma_f32_16x16x32_bf16(pf[1], vf, o_acc[1][ni], 0, 0, 0);
      }
    }
    __builtin_amdgcn_s_setprio(0);
  }

  // ---- epilogue: l_acc reg r holds l for q-row qb*16+quad*4+r — exactly
  //      the o_acc row layout; no cross-lane reduction needed.
  float rl[2][4];
#pragma unroll
  for (int qb = 0; qb < 2; qb++)
#pragma unroll
    for (int r = 0; r < 4; r++) rl[qb][r] = 1.0f / l_acc[qb][r];
#pragma unroll
  for (int qb = 0; qb < 2; qb++) {
    const int q0 = qw + qb * 16 + quad * 4;
#pragma unroll
    for (int ni = 0; ni < 4; ni++)
#pragma unroll
      for (int r = 0; r < 4; r++)
        Ob[(size_t)(b * S + q0 + r) * D + h * 64 + ni * 16 + l15] =
            f2bf(o_acc[qb][ni][r] * rl[qb][r]);
  }
}

// ---------------------------------------------------------------- launch
extern "C" void kernel_launch(void* const* d_in, const int* in_sizes, int n_in,
                              void* d_out, int out_size, void* d_ws, size_t ws_size,
                              hipStream_t stream) {
  const int M = 8192, N = 1024, K = 1024;
  const float* q    = (const float*)d_in[0];
  const float* k    = (const float*)d_in[1];
  const float* v    = (const float*)d_in[2];
  const int*   mask = (const int*)d_in[3];
  const float* Wq = (const float*)d_in[4];
  const float* bq = (const float*)d_in[5];
  const float* Wk = (const float*)d_in[6];
  const float* bk = (const float*)d_in[7];
  const float* Wv = (const float*)d_in[8];
  const float* bv = (const float*)d_in[9];
  const float* Wo = (const float*)d_in[10];
  const float* bo = (const float*)d_in[11];

  const size_t MN = (size_t)M * N;                  // 8388608
  const float QSC = 0.125f * 1.44269504f;           // (1/sqrt(dk)) * log2(e)

  dim3 bb(256);
  dim3 gg(N / GN, M / GM);

  const size_t need_batched = (6 * MN + 4 * 1048576) * sizeof(u16);  // ~109 MB
  if (ws_size >= need_batched) {
    u16* Ax  = (u16*)d_ws;            // 3*MN: q,k,v bf16 (reused as Ob later)
    u16* Qb  = Ax + 3 * MN;
    u16* Kb  = Ax + 4 * MN;
    u16* VtG = Ax + 5 * MN;           // V^T: [1024 dims][8192 tokens]
    u16* Wc  = Ax + 6 * MN;           // 4 x 1M bf16 weights
    u16* Ob  = Ax;                    // attn output (QKV gemms done reading)

    cvt_w4<<<dim3(512, 4), bb, 0, stream>>>(Wq, Wk, Wv, Wo, Wc);
    cvt_x3<<<dim3(4096, 3), bb, 0, stream>>>(q, k, v, Ax);
    gemm_qkv2<<<dim3(N / HN, M / HM, 3), dim3(512), 0, stream>>>(
        Ax, Wc, bq, bk, bv, Qb, Kb, VtG, QSC);
    attn_fused<<<dim3(16, 64), bb, 0, stream>>>(Qb, Kb, VtG, mask, Ob);
    gemm_bb<float, false><<<gg, bb, 0, stream>>>(Ob, Wc + 3 * 1048576, bo,
                                                 (float*)d_out, M, N, K, 1.0f);
  } else {
    // sequential fallback (round-5 layout, 75.5 MB)
    u16* Qb  = (u16*)d_ws;
    u16* Kb  = Qb + MN;
    u16* VtG = Kb + MN;
    u16* Ob  = VtG + MN;
    u16* Wc  = Ob + MN;
    const int xblk = (int)(MN / (256 * 8));

    cvt_w4<<<dim3(512, 4), bb, 0, stream>>>(Wq, Wk, Wv, Wo, Wc);

    cvt_x<<<xblk, bb, 0, stream>>>(q, Ob, M * N);
    gemm_bb<u16, false><<<gg, bb, 0, stream>>>(Ob, Wc + 0 * 1048576, bq, Qb, M, N, K, QSC);
    cvt_x<<<xblk, bb, 0, stream>>>(k, Ob, M * N);
    gemm_bb<u16, false><<<gg, bb, 0, stream>>>(Ob, Wc + 1 * 1048576, bk, Kb, M, N, K, 1.0f);
    cvt_x<<<xblk, bb, 0, stream>>>(v, Ob, M * N);
    gemm_bb<u16, true><<<gg, bb, 0, stream>>>(Ob, Wc + 2 * 1048576, bv, VtG, M, N, K, 1.0f);

    attn_fused<<<dim3(16, 64), bb, 0, stream>>>(Qb, Kb, VtG, mask, Ob);

    gemm_bb<float, false><<<gg, bb, 0, stream>>>(Ob, Wc + 3 * 1048576, bo,
                                                 (float*)d_out, M, N, K, 1.0f);
  }
}